// Round 1
// baseline (288.281 us; speedup 1.0000x reference)
//
#include <hip/hip_runtime.h>
#include <stdint.h>

#define BATCH 8
#define LSEQ 16384
#define HDIM 128
#define KSZ 65
#define PADW 32
#define LH (LSEQ*HDIM)
#define TL 256
#define NROWS (TL + 2*PADW)     // 320 staged Q rows
#define LBLKS (LSEQ/TL)         // 64
#define EXP_SHIFT 20.0f

#define WS_WBF_OFF 4096         // bf16 W starts here; gsum f32[1024] at offset 0

typedef __attribute__((ext_vector_type(8))) short bf16x8;
typedef __attribute__((ext_vector_type(4))) short bf16x4;
typedef __attribute__((ext_vector_type(4))) float f32x4;

__device__ __forceinline__ unsigned short f2bf(float f) {
  unsigned int u = __float_as_uint(f);
  return (unsigned short)((u + 0x7FFFu + ((u >> 16) & 1u)) >> 16);  // RNE
}

// ---------------- K0: W [o][i][k] f32  ->  ws  [k][o][i ^ ((o&7)<<3)] bf16 ----------------
__global__ __launch_bounds__(256) void wcvt_kernel(const float* __restrict__ W,
                                                   unsigned short* __restrict__ Wbf) {
  __shared__ float lw[KSZ*HDIM];
  const int o = blockIdx.x;
  const float* src = W + (size_t)o * (HDIM*KSZ);
  for (int t = threadIdx.x; t < HDIM*KSZ; t += 256) lw[t] = src[t];
  __syncthreads();
  const int osw = (o & 7) << 3;
  for (int idx = threadIdx.x; idx < KSZ*HDIM; idx += 256) {
    const int k = idx >> 7;      // 0..64
    const int i = idx & 127;
    Wbf[(size_t)k*(HDIM*HDIM) + o*HDIM + (i ^ osw)] = f2bf(lw[i*KSZ + k]);
  }
}

// async-copy one 32KB W tap (already swizzled in ws) linearly into LDS
__device__ __forceinline__ void stage_w(const unsigned short* __restrict__ Wbf, int k,
                                        unsigned short* dst, int w, int lane) {
  const char* gbase = (const char*)(Wbf + (size_t)k * (HDIM*HDIM));
  char* lbase = (char*)dst;
#pragma unroll
  for (int r = 0; r < 4; ++r) {
    const int off = r*8192 + w*1024;   // 8 waves * 64 lanes * 16B = 8192B per round
    __builtin_amdgcn_global_load_lds(
        (const __attribute__((address_space(1))) unsigned int*)(gbase + off + lane*16),
        (__attribute__((address_space(3))) unsigned int*)(lbase + off),
        16, 0, 0);
  }
}

// ---------------- K1: conv GEMM + gate + exp + per-(b,h) partial sums ----------------
__global__ __launch_bounds__(512, 2) void conv_gate_kernel(
    const float* __restrict__ Qm, const float* __restrict__ Km,
    const unsigned short* __restrict__ Wbf,
    float* __restrict__ Eout, float* __restrict__ gsum) {

  __shared__ __align__(16) unsigned short Qs[NROWS*HDIM];     // 81920 B, swizzled
  __shared__ __align__(16) unsigned short Ws[2][HDIM*HDIM];   // 65536 B, swizzled

  const int tid  = threadIdx.x;
  const int lane = tid & 63;
  const int w    = tid >> 6;    // 0..7
  const int wr   = w >> 1;      // 0..3 : 64-row band
  const int wc   = w & 1;       // 0..1 : 64-col band
  const int l15  = lane & 15;
  const int hi   = lane >> 4;   // 0..3

  const int bx = blockIdx.x;
  const int b  = bx >> 6;
  const int l0 = (bx & 63) << 8;   // * TL

  // ---- stage Q rows [l0-32, l0+TL+32) as swizzled bf16 ----
  {
    const int r0 = tid >> 5;            // 0..15
    const int c4 = (tid & 31) << 2;     // 0..124 step 4
    const float* qbase = Qm + (size_t)b*LH + c4;
#pragma unroll
    for (int it = 0; it < NROWS/16; ++it) {
      const int r = it*16 + r0;
      const int grow = l0 - PADW + r;
      bf16x4 pk = {0, 0, 0, 0};
      if (grow >= 0 && grow < LSEQ) {
        const float4 qv = *(const float4*)(qbase + (size_t)grow*HDIM);
        pk[0] = (short)f2bf(qv.x); pk[1] = (short)f2bf(qv.y);
        pk[2] = (short)f2bf(qv.z); pk[3] = (short)f2bf(qv.w);
      }
      *(bf16x4*)(&Qs[r*HDIM + (c4 ^ ((r & 7) << 3))]) = pk;
    }
  }

  stage_w(Wbf, 0, &Ws[0][0], w, lane);

  // B-frag LDS offsets are tap-invariant: precompute (nf x kk)
  int boff[4][4];
#pragma unroll
  for (int nf = 0; nf < 4; ++nf) {
    const int o  = wc*64 + nf*16 + l15;
    const int xr = (o & 7) << 3;
#pragma unroll
    for (int kk = 0; kk < 4; ++kk)
      boff[nf][kk] = o*HDIM + ((kk*32 + hi*8) ^ xr);
  }

  f32x4 acc[4][4] = {};

  __syncthreads();   // Q staged + W tap0 landed (implicit vmcnt(0) drain)

  int buf = 0;
  for (int k = 0; k < KSZ; ++k) {
    if (k < KSZ-1) stage_w(Wbf, k+1, &Ws[buf^1][0], w, lane);   // prefetch next tap
    const unsigned short* wsrc = &Ws[buf][0];
#pragma unroll
    for (int kk = 0; kk < 4; ++kk) {
      bf16x8 afr[4], bfr[4];
      const int i0 = kk*32 + hi*8;
#pragma unroll
      for (int mf = 0; mf < 4; ++mf) {
        const int row = k + wr*64 + mf*16 + l15;   // sliding window: tap k shifts A by one row
        afr[mf] = *(const bf16x8*)(&Qs[row*HDIM + (i0 ^ ((row & 7) << 3))]);
      }
#pragma unroll
      for (int nf = 0; nf < 4; ++nf)
        bfr[nf] = *(const bf16x8*)(&wsrc[boff[nf][kk]]);
#pragma unroll
      for (int mf = 0; mf < 4; ++mf)
#pragma unroll
        for (int nf = 0; nf < 4; ++nf)
          acc[mf][nf] = __builtin_amdgcn_mfma_f32_16x16x32_bf16(afr[mf], bfr[nf], acc[mf][nf], 0, 0, 0);
    }
    __syncthreads();   // drains prefetch (vmcnt 0) + releases Ws[buf] for overwrite
    buf ^= 1;
  }

  // ---- epilogue: gate by K, exp-shift, store E, per-column partial sums ----
  float psum[4] = {0.f, 0.f, 0.f, 0.f};
#pragma unroll
  for (int mf = 0; mf < 4; ++mf) {
#pragma unroll
    for (int j = 0; j < 4; ++j) {
      const int row = wr*64 + mf*16 + hi*4 + j;           // C/D: row=(lane>>4)*4+reg (m89)
      const size_t gb = (size_t)b*LH + (size_t)(l0 + row)*HDIM + wc*64 + l15;
#pragma unroll
      for (int nf = 0; nf < 4; ++nf) {                    // C/D: col=lane&15
        const float s = acc[mf][nf][j] * Km[gb + nf*16];
        const float e = __expf(s - EXP_SHIFT);
        Eout[gb + nf*16] = e;
        psum[nf] += e;
      }
    }
  }
#pragma unroll
  for (int nf = 0; nf < 4; ++nf) {      // fold the 4 row-groups (lanes ^16, ^32)
    psum[nf] += __shfl_xor(psum[nf], 16);
    psum[nf] += __shfl_xor(psum[nf], 32);
  }
  const float myv = (hi == 0) ? psum[0] : (hi == 1) ? psum[1] : (hi == 2) ? psum[2] : psum[3];
  atomicAdd(&gsum[b*HDIM + wc*64 + hi*16 + l15], myv);
}

// ---------------- K2: Z = E * V / gsum (in place on d_out) ----------------
__global__ __launch_bounds__(256) void finalize_kernel(float* __restrict__ out,
                                                       const float* __restrict__ V,
                                                       const float* __restrict__ gsum) {
  const int total4 = (BATCH*LH) >> 2;
  const int stride = gridDim.x * blockDim.x;
  for (int f = blockIdx.x*blockDim.x + threadIdx.x; f < total4; f += stride) {
    const float4 e = ((const float4*)out)[f];
    const float4 v = ((const float4*)V)[f];
    const int e0 = f << 2;
    const float* gs = gsum + ((e0 >> 21) << 7) + (e0 & 127);   // b*128 + h0
    float4 z;
    z.x = e.x * v.x / gs[0];
    z.y = e.y * v.y / gs[1];
    z.z = e.z * v.z / gs[2];
    z.w = e.w * v.w / gs[3];
    ((float4*)out)[f] = z;
  }
}

extern "C" void kernel_launch(void* const* d_in, const int* in_sizes, int n_in,
                              void* d_out, int out_size, void* d_ws, size_t ws_size,
                              hipStream_t stream) {
  (void)in_sizes; (void)n_in; (void)out_size; (void)ws_size;
  const float* Q = (const float*)d_in[0];
  const float* K = (const float*)d_in[1];
  const float* V = (const float*)d_in[2];
  const float* W = (const float*)d_in[3];
  float* out  = (float*)d_out;
  float* gsum = (float*)d_ws;
  unsigned short* Wbf = (unsigned short*)((char*)d_ws + WS_WBF_OFF);

  hipMemsetAsync(d_ws, 0, BATCH*HDIM*sizeof(float), stream);          // gsum = 0
  wcvt_kernel<<<HDIM, 256, 0, stream>>>(W, Wbf);                      // W -> bf16, swizzled
  conv_gate_kernel<<<BATCH*LBLKS, 512, 0, stream>>>(Q, K, Wbf, out, gsum);
  finalize_kernel<<<2048, 256, 0, stream>>>(out, V, gsum);
}